// Round 9
// baseline (237.552 us; speedup 1.0000x reference)
//
#include <hip/hip_runtime.h>

#define EG   16000   // graph edges
#define NG   1000    // graph_size (block rows/cols)
#define BB   32      // batch
#define SIZE 16000   // feature length (NG*16)
#define CAP  64      // bucket capacity per bin (Poisson(16): P(>64) ~ 1e-18)

typedef float f32x4 __attribute__((ext_vector_type(4)));

#define EPS_SIG   0.0009765625f   // 2^-10
#define TARGET1   0.9765625f      // 1000 * 2^-10 (exact in f32)
#define SIG_IDX   15              // out[batch0, feature 15]: not a counter cell,
                                  // owned by block 0 (overwritten in its epilogue)

// ---- single fused kernel: bucket -> out-resident grid barrier -> spmm ----
// Grid barrier WITHOUT cooperative launch (graph-capture incompatible, r8):
// 'out' is zeroed in-stream before every launch, so bin counters live at
// out[batch0, g*16] (inside bin g's own territory: only its reader overwrites)
// and the all-produced signal at out[batch0, 15] (monotonic += 2^-10 x 1000,
// exact; owner block 0 overwrites only after global completion).
// Cross-block traffic = agent-scope atomics (per-XCD L2 non-coherent, G16).
// spmm body = round-7 verbatim (proven, no atomics, fused bias).
__global__ __launch_bounds__(256, 4) void fused_kernel(
    const float* __restrict__ wm, const float* __restrict__ wlv,
    const float* __restrict__ ew, const float* __restrict__ x,
    const float* __restrict__ bm, const float* __restrict__ blv,
    const float* __restrict__ eb, const int* __restrict__ rows,
    const int* __restrict__ cols, int* __restrict__ bucket,
    float* __restrict__ out)
{
    __shared__ f32x4 vt[2][4][64];    // [buf][slot][i*4+jg]  sampled weights
    __shared__ f32x4 xs[2][4][160];   // [buf][slot][b*5+q]   x rows, pad-5
    __shared__ int   sl[CAP];         // packed (e<<10)|t1 for this bin

    int g   = blockIdx.x;
    int tid = threadIdx.x;

    // ---- phase 1: produce 16 edges (block g owns edges [16g, 16g+16)) ----
    if (tid < 16) {
        int e  = (g << 4) + tid;
        int t0 = rows[(long)e << 8] >> 4;   // rows[e*256] = t0*16
        int t1 = cols[(long)e << 8] >> 4;   // cols[e*256] = t1*16
        float old = __hip_atomic_fetch_add(&out[t0 << 4], 1.0f,
                                           __ATOMIC_RELAXED, __HIP_MEMORY_SCOPE_AGENT);
        int pos = (int)old;                 // exact: counter counts <= ~45 << 2^24
        if (pos >= 0 && pos < CAP)
            __hip_atomic_store(&bucket[t0 * CAP + pos], (e << 10) | t1,
                               __ATOMIC_RELEASE, __HIP_MEMORY_SCOPE_AGENT);
    }
    __syncthreads();                        // order lane stores before tid0's release

    // ---- phase 2: signal + spin (out-resident barrier) ----
    if (tid == 0) {
        __hip_atomic_fetch_add(&out[SIG_IDX], EPS_SIG,
                               __ATOMIC_RELEASE, __HIP_MEMORY_SCOPE_AGENT);
        int guard = 0;
        while (__hip_atomic_load(&out[SIG_IDX], __ATOMIC_ACQUIRE,
                                 __HIP_MEMORY_SCOPE_AGENT) < TARGET1
               && ++guard < 4096) {
            __builtin_amdgcn_s_sleep(8);    // ~512 cy/poll: low L2 pressure
        }
    }
    __syncthreads();

    // ---- phase 3: read own bin (counter cell is in our own territory) ----
    int n = (int)__hip_atomic_load(&out[g << 4], __ATOMIC_ACQUIRE,
                                   __HIP_MEMORY_SCOPE_AGENT);
    n = n < 0 ? 0 : (n > CAP ? CAP : n);
    if (tid < n)
        sl[tid] = __hip_atomic_load(&bucket[g * CAP + tid],
                                    __ATOMIC_ACQUIRE, __HIP_MEMORY_SCOPE_AGENT);
    __syncthreads();

    // ---- phase 4: spmm (round-7 verbatim) ----
    int wave = tid >> 6;              // edge slot 0..3
    int lane = tid & 63;
    int jg   = lane & 3;
    int cb2  = lane >> 2;             // 0..15

    f32x4 acc0 = {0.f,0.f,0.f,0.f}, acc1 = {0.f,0.f,0.f,0.f};
    f32x4 m4, l4, g4, xv0, xv1;       // staged regs (in flight across compute)
    int iters = (n + 3) >> 2;
    bool vcur = false, vnxt = false;

    auto issue = [&](int idx) -> bool {     // global loads only (no LDS writes)
        bool val = idx < n;
        if (val) {                          // wave-uniform branch
            int pk = sl[idx];
            int e  = pk >> 10;
            int t1 = pk & 1023;
            long wq = ((long)e << 6) + lane;
            m4 = ((const f32x4*)wm)[wq];    // 3 x b128, coalesced 1KB/wave
            l4 = ((const f32x4*)wlv)[wq];
            g4 = ((const f32x4*)ew)[wq];
            const f32x4* x4 = (const f32x4*)x;
            int c0 = lane, c1 = lane + 64;  // chunk = (b = c>>2, q = c&3)
            xv0 = x4[(long)(c0 >> 2) * (SIZE/4) + (t1 << 2) + (c0 & 3)];
            xv1 = x4[(long)(c1 >> 2) * (SIZE/4) + (t1 << 2) + (c1 & 3)];
        }
        return val;
    };
    auto writeb = [&](int buf, bool val) {  // vmcnt wait lands here (T14)
        if (val) {
            f32x4 v;
            v.x = g4.x * __expf(l4.x) + m4.x;
            v.y = g4.y * __expf(l4.y) + m4.y;
            v.z = g4.z * __expf(l4.z) + m4.z;
            v.w = g4.w * __expf(l4.w) + m4.w;
            vt[buf][wave][lane] = v;        // chunk lane = (i=lane>>2, jg=lane&3)
            int c0 = lane, c1 = lane + 64;
            xs[buf][wave][(c0 >> 2) * 5 + (c0 & 3)] = xv0;
            xs[buf][wave][(c1 >> 2) * 5 + (c1 & 3)] = xv1;
        }
    };
    auto compute = [&](int buf, bool val) {
        if (!val) return;                   // wave-uniform
        f32x4 a0 = xs[buf][wave][ cb2       * 5 + 0];
        f32x4 a1 = xs[buf][wave][ cb2       * 5 + 1];
        f32x4 a2 = xs[buf][wave][ cb2       * 5 + 2];
        f32x4 a3 = xs[buf][wave][ cb2       * 5 + 3];
        f32x4 b0 = xs[buf][wave][(cb2 + 16) * 5 + 0];
        f32x4 b1 = xs[buf][wave][(cb2 + 16) * 5 + 1];
        f32x4 b2 = xs[buf][wave][(cb2 + 16) * 5 + 2];
        f32x4 b3 = xs[buf][wave][(cb2 + 16) * 5 + 3];
        float xra[16] = {a0.x,a0.y,a0.z,a0.w, a1.x,a1.y,a1.z,a1.w,
                         a2.x,a2.y,a2.z,a2.w, a3.x,a3.y,a3.z,a3.w};
        float xrb[16] = {b0.x,b0.y,b0.z,b0.w, b1.x,b1.y,b1.z,b1.w,
                         b2.x,b2.y,b2.z,b2.w, b3.x,b3.y,b3.z,b3.w};
        #pragma unroll
        for (int i = 0; i < 16; ++i) {
            f32x4 w = vt[buf][wave][(i << 2) + jg];  // 16-lane broadcast chunks
            acc0 += w * xra[i];             // 4 FMA (static index after unroll)
            acc1 += w * xrb[i];
        }
    };

    // prologue
    vcur = issue(wave);
    writeb(0, vcur);
    __syncthreads();
    // main loop: one barrier per 4-edge iteration
    for (int it = 0; it < iters; ++it) {
        bool more = (it + 1 < iters);
        if (more) vnxt = issue(((it + 1) << 2) + wave);  // globals in flight
        compute(it & 1, vcur);                            // LDS+VALU overlap
        if (more) writeb((it + 1) & 1, vnxt);
        __syncthreads();
        vcur = vnxt;
    }

    // ---- epilogue: cross-slot reduce + fused bias + exclusive store ----
    f32x4* sred = &xs[0][0][0];            // overlay: xs dead after last barrier
    sred[(wave << 7) + (lane << 1) + 0] = acc0;
    sred[(wave << 7) + (lane << 1) + 1] = acc1;
    __syncthreads();
    if (tid < 128) {
        int cb  = tid >> 2;                // batch 0..31
        int jgf = tid & 3;
        int h   = cb >> 4;                 // which accumulator half
        int sl_ = ((cb & 15) << 2) + jgf;  // lane in slot
        f32x4 s = sred[(0 << 7) + (sl_ << 1) + h]
                + sred[(1 << 7) + (sl_ << 1) + h]
                + sred[(2 << 7) + (sl_ << 1) + h]
                + sred[(3 << 7) + (sl_ << 1) + h];
        int r0 = (g << 4) + (jgf << 2);    // 16B-aligned
        f32x4 b4 = *(const f32x4*)&bm[r0];
        f32x4 v4 = *(const f32x4*)&blv[r0];
        f32x4 e4 = *(const f32x4*)&eb[r0];
        f32x4 o;
        o.x = s.x + (e4.x * __expf(v4.x) + b4.x);
        o.y = s.y + (e4.y * __expf(v4.y) + b4.y);
        o.z = s.z + (e4.z * __expf(v4.z) + b4.z);
        o.w = s.w + (e4.w * __expf(v4.w) + b4.w);
        *(f32x4*)&out[(long)cb * SIZE + r0] = o;   // overwrites counter/signal cells
    }
    if (g == 0 && tid == 0) out[(long)BB * SIZE] = 0.0f;   // kl scalar
}

extern "C" void kernel_launch(void* const* d_in, const int* in_sizes, int n_in,
                              void* d_out, int out_size, void* d_ws, size_t ws_size,
                              hipStream_t stream) {
    const float* x   = (const float*)d_in[0];
    const float* wm  = (const float*)d_in[1];
    const float* wlv = (const float*)d_in[2];
    const float* bm  = (const float*)d_in[3];
    const float* blv = (const float*)d_in[4];
    const float* ew  = (const float*)d_in[5];
    const float* eb  = (const float*)d_in[6];
    const int* rows  = (const int*)d_in[7];
    const int* cols  = (const int*)d_in[8];
    float* out = (float*)d_out;

    int* bucket = (int*)d_ws;             // 1000*64 ints = 256KB

    fused_kernel<<<NG, 256, 0, stream>>>(wm, wlv, ew, x, bm, blv, eb,
                                         rows, cols, bucket, out);
}

// Round 10
// 133.020 us; speedup vs baseline: 1.7858x; 1.7858x over previous
//
#include <hip/hip_runtime.h>

#define EG   16000   // graph edges
#define NG   1000    // graph_size (block rows/cols)
#define BB   32      // batch
#define SIZE 16000   // feature length (NG*16)
#define CAP  64      // per-bin capacity (Poisson(16): P(>64) ~ 1e-18)

typedef float f32x4 __attribute__((ext_vector_type(4)));

// ---- kernel 1: gather strided edge headers into dense pk[e]=(t0<<10)|t1 ----
// Writes every entry each launch: ws poison is never read. No memset needed.
__global__ __launch_bounds__(256) void pack_kernel(
    const int* __restrict__ rows, const int* __restrict__ cols,
    int* __restrict__ pk)
{
    int e = blockIdx.x * 256 + threadIdx.x;
    if (e < EG) {
        int t0 = rows[(long)e << 8] >> 4;   // rows[e*256] = t0*16
        int t1 = cols[(long)e << 8] >> 4;   // cols[e*256] = t1*16
        pk[e] = (t0 << 10) | t1;            // 20 bits
    }
}

// ---- kernel 2: scan dense pk for own bin, then r7 spmm body (no atomics) ----
// out[b, g*16+j] = bias + sum_{e: t0(e)=g} sum_i v_e[i*16+j] * x[b, t1_e*16+i]
// Scan: 64KB dense array, int4 coalesced loads (L2-resident broadcast),
// LDS-atomic compaction. Then 4 edges in flight (1 wave each), T14 staging,
// fused bias, exclusive f32x4 stores.
// NOTE (r8/r9): no in-kernel grid barriers -- cooperative launch breaks graph
// capture; spin-on-global barriers cost ~130us (guard exhaustion). The
// dispatch boundary is the cheapest grid barrier (~5us).
__global__ __launch_bounds__(256, 4) void spmm_kernel(
    const float* __restrict__ wm, const float* __restrict__ wlv,
    const float* __restrict__ ew, const float* __restrict__ x,
    const float* __restrict__ bm, const float* __restrict__ blv,
    const float* __restrict__ eb, const int* __restrict__ pk,
    float* __restrict__ out)
{
    __shared__ f32x4 vt[2][4][64];    // [buf][slot][i*4+jg]  sampled weights
    __shared__ f32x4 xs[2][4][160];   // [buf][slot][b*5+q]   x rows, pad-5
    __shared__ int   sl[CAP];         // packed (e<<10)|t1 for this bin
    __shared__ int   scnt;

    int g   = blockIdx.x;
    int tid = threadIdx.x;

    // ---- phase 1: scan + compact own edges (e is the array index) ----
    if (tid == 0) scnt = 0;
    __syncthreads();
    const int4* pk4 = (const int4*)pk;
    for (int c = tid; c < EG / 4; c += 256) {      // 16 coalesced iterations
        int4 v = pk4[c];
        int e0 = c << 2;
        if ((v.x >> 10) == g) { int p = atomicAdd(&scnt, 1); if (p < CAP) sl[p] = ((e0    ) << 10) | (v.x & 1023); }
        if ((v.y >> 10) == g) { int p = atomicAdd(&scnt, 1); if (p < CAP) sl[p] = ((e0 + 1) << 10) | (v.y & 1023); }
        if ((v.z >> 10) == g) { int p = atomicAdd(&scnt, 1); if (p < CAP) sl[p] = ((e0 + 2) << 10) | (v.z & 1023); }
        if ((v.w >> 10) == g) { int p = atomicAdd(&scnt, 1); if (p < CAP) sl[p] = ((e0 + 3) << 10) | (v.w & 1023); }
    }
    __syncthreads();
    int n = scnt; n = n < CAP ? n : CAP;

    // ---- phase 2: spmm (round-7 verbatim) ----
    int wave = tid >> 6;              // edge slot 0..3
    int lane = tid & 63;
    int jg   = lane & 3;
    int cb2  = lane >> 2;             // 0..15

    f32x4 acc0 = {0.f,0.f,0.f,0.f}, acc1 = {0.f,0.f,0.f,0.f};
    f32x4 m4, l4, g4, xv0, xv1;       // staged regs (in flight across compute)
    int iters = (n + 3) >> 2;
    bool vcur = false, vnxt = false;

    auto issue = [&](int idx) -> bool {     // global loads only (no LDS writes)
        bool val = idx < n;
        if (val) {                          // wave-uniform branch
            int pkv = sl[idx];
            int e   = pkv >> 10;
            int t1  = pkv & 1023;
            long wq = ((long)e << 6) + lane;
            m4 = ((const f32x4*)wm)[wq];    // 3 x b128, coalesced 1KB/wave
            l4 = ((const f32x4*)wlv)[wq];
            g4 = ((const f32x4*)ew)[wq];
            const f32x4* x4 = (const f32x4*)x;
            int c0 = lane, c1 = lane + 64;  // chunk = (b = c>>2, q = c&3)
            xv0 = x4[(long)(c0 >> 2) * (SIZE/4) + (t1 << 2) + (c0 & 3)];
            xv1 = x4[(long)(c1 >> 2) * (SIZE/4) + (t1 << 2) + (c1 & 3)];
        }
        return val;
    };
    auto writeb = [&](int buf, bool val) {  // vmcnt wait lands here (T14)
        if (val) {
            f32x4 v;
            v.x = g4.x * __expf(l4.x) + m4.x;
            v.y = g4.y * __expf(l4.y) + m4.y;
            v.z = g4.z * __expf(l4.z) + m4.z;
            v.w = g4.w * __expf(l4.w) + m4.w;
            vt[buf][wave][lane] = v;        // chunk lane = (i=lane>>2, jg=lane&3)
            int c0 = lane, c1 = lane + 64;
            xs[buf][wave][(c0 >> 2) * 5 + (c0 & 3)] = xv0;
            xs[buf][wave][(c1 >> 2) * 5 + (c1 & 3)] = xv1;
        }
    };
    auto compute = [&](int buf, bool val) {
        if (!val) return;                   // wave-uniform
        f32x4 a0 = xs[buf][wave][ cb2       * 5 + 0];
        f32x4 a1 = xs[buf][wave][ cb2       * 5 + 1];
        f32x4 a2 = xs[buf][wave][ cb2       * 5 + 2];
        f32x4 a3 = xs[buf][wave][ cb2       * 5 + 3];
        f32x4 b0 = xs[buf][wave][(cb2 + 16) * 5 + 0];
        f32x4 b1 = xs[buf][wave][(cb2 + 16) * 5 + 1];
        f32x4 b2 = xs[buf][wave][(cb2 + 16) * 5 + 2];
        f32x4 b3 = xs[buf][wave][(cb2 + 16) * 5 + 3];
        float xra[16] = {a0.x,a0.y,a0.z,a0.w, a1.x,a1.y,a1.z,a1.w,
                         a2.x,a2.y,a2.z,a2.w, a3.x,a3.y,a3.z,a3.w};
        float xrb[16] = {b0.x,b0.y,b0.z,b0.w, b1.x,b1.y,b1.z,b1.w,
                         b2.x,b2.y,b2.z,b2.w, b3.x,b3.y,b3.z,b3.w};
        #pragma unroll
        for (int i = 0; i < 16; ++i) {
            f32x4 w = vt[buf][wave][(i << 2) + jg];  // 16-lane broadcast chunks
            acc0 += w * xra[i];             // 4 FMA (static index after unroll)
            acc1 += w * xrb[i];
        }
    };

    // prologue
    vcur = issue(wave);
    writeb(0, vcur);
    __syncthreads();
    // main loop: one barrier per 4-edge iteration
    for (int it = 0; it < iters; ++it) {
        bool more = (it + 1 < iters);
        if (more) vnxt = issue(((it + 1) << 2) + wave);  // globals in flight
        compute(it & 1, vcur);                            // LDS+VALU overlap
        if (more) writeb((it + 1) & 1, vnxt);
        __syncthreads();
        vcur = vnxt;
    }

    // ---- epilogue: cross-slot reduce + fused bias + exclusive store ----
    f32x4* sred = &xs[0][0][0];            // overlay: xs dead after last barrier
    sred[(wave << 7) + (lane << 1) + 0] = acc0;
    sred[(wave << 7) + (lane << 1) + 1] = acc1;
    __syncthreads();
    if (tid < 128) {
        int cb  = tid >> 2;                // batch 0..31
        int jgf = tid & 3;
        int h   = cb >> 4;                 // which accumulator half
        int sl_ = ((cb & 15) << 2) + jgf;  // lane in slot
        f32x4 s = sred[(0 << 7) + (sl_ << 1) + h]
                + sred[(1 << 7) + (sl_ << 1) + h]
                + sred[(2 << 7) + (sl_ << 1) + h]
                + sred[(3 << 7) + (sl_ << 1) + h];
        int r0 = (g << 4) + (jgf << 2);    // 16B-aligned
        f32x4 b4 = *(const f32x4*)&bm[r0];
        f32x4 v4 = *(const f32x4*)&blv[r0];
        f32x4 e4 = *(const f32x4*)&eb[r0];
        f32x4 o;
        o.x = s.x + (e4.x * __expf(v4.x) + b4.x);
        o.y = s.y + (e4.y * __expf(v4.y) + b4.y);
        o.z = s.z + (e4.z * __expf(v4.z) + b4.z);
        o.w = s.w + (e4.w * __expf(v4.w) + b4.w);
        *(f32x4*)&out[(long)cb * SIZE + r0] = o;
    }
    if (g == 0 && tid == 0) out[(long)BB * SIZE] = 0.0f;   // kl scalar
}

extern "C" void kernel_launch(void* const* d_in, const int* in_sizes, int n_in,
                              void* d_out, int out_size, void* d_ws, size_t ws_size,
                              hipStream_t stream) {
    const float* x   = (const float*)d_in[0];
    const float* wm  = (const float*)d_in[1];
    const float* wlv = (const float*)d_in[2];
    const float* bm  = (const float*)d_in[3];
    const float* blv = (const float*)d_in[4];
    const float* ew  = (const float*)d_in[5];
    const float* eb  = (const float*)d_in[6];
    const int* rows  = (const int*)d_in[7];
    const int* cols  = (const int*)d_in[8];
    float* out = (float*)d_out;

    int* pk = (int*)d_ws;                 // 16000 ints = 64KB dense edge headers

    pack_kernel<<<(EG + 255) / 256, 256, 0, stream>>>(rows, cols, pk);
    spmm_kernel<<<NG, 256, 0, stream>>>(wm, wlv, ew, x, bm, blv, eb, pk, out);
}